// Round 25
// baseline (122.160 us; speedup 1.0000x reference)
//
#include <hip/hip_runtime.h>
#include <stdint.h>

#define NH 16
#define SEQ 2048
#define DMODEL 1024
#define HD 64
#define NBATCH 2
#define MTOT (NBATCH * SEQ)              // 4096 rows for the big GEMMs
#define QSCALE 0.17677669529663687f      // 1/sqrt(B*H) = 1/sqrt(32)  (faithful bug)
#define LOG2E 1.4426950408889634f

typedef __bf16 bf16x8 __attribute__((ext_vector_type(8)));
typedef float f32x4 __attribute__((ext_vector_type(4)));
typedef float f32x16 __attribute__((ext_vector_type(16)));
typedef unsigned uint4v __attribute__((ext_vector_type(4)));

// round-to-nearest-even fp32 -> bf16 bit pattern
__device__ __forceinline__ unsigned short bf16u(float x) {
  unsigned u = __builtin_bit_cast(unsigned, x);
  u += 0x7fffu + ((u >> 16) & 1u);
  return (unsigned short)(u >> 16);
}

// 2^x via v_exp_f32 (ISA: D = 2^S0)
__device__ __forceinline__ float exp2_fast(float x) {
  float r;
  asm("v_exp_f32 %0, %1" : "=v"(r) : "v"(x));
  return r;
}

__device__ __forceinline__ f32x4 mfma16(bf16x8 a, bf16x8 b, f32x4 c) {
  return __builtin_amdgcn_mfma_f32_16x16x32_bf16(a, b, c, 0, 0, 0);
}
__device__ __forceinline__ f32x16 mfma32(bf16x8 a, bf16x8 b, f32x16 c) {
  return __builtin_amdgcn_mfma_f32_32x32x16_bf16(a, b, c, 0, 0, 0);
}

__device__ __forceinline__ void gl16(const void* g, void* l) {
  __builtin_amdgcn_global_load_lds(
      (const __attribute__((address_space(1))) void*)g,
      (__attribute__((address_space(3))) void*)l, 16, 0, 0);
}

// pack 2 f32 -> 2 bf16 in one u32 (lo = a, hi = b)
__device__ __forceinline__ unsigned cvtpk(float a, float b) {
  unsigned r;
  asm("v_cvt_pk_bf16_f32 %0, %1, %2" : "=v"(r) : "v"(a), "v"(b));
  return r;
}

// NOTE: permlane32_swap reduces BANNED (R4/R10); __shfl_xor(32) proven.
// min-waves clamp BANNED on attn (R11 spill).  Register-dbuf of K/V tiles
// BANNED (R15/R21).  attn loop reorders BANNED (R16/R22 regressed).
// R24: XCD swizzle on qkv was NEUTRAL -> L3-thrash theory refuted; limiter
// is the 3-blocks/CU barrier convoy (930 cyc MFMA work vs 3900 cyc wall).
// R25: 256x256-tile gemm_qkv, 512 threads, 1 block/CU — one barrier group
// per CU (no convoy), 32 MFMA/wave/barrier (2x amortization).  Same proven
// triple-buffer + counted vmcnt(4) + s_barrier + (row>>1)&3 swizzle; same
// epilogue algebra.  attn/prep/gemm_out = champion, untouched.

// ---- fused prep: cast x (fp32->bf16) + transpose/cast W ----
__global__ __launch_bounds__(256) void prep_kernel(
    const float* __restrict__ x0, const float* __restrict__ x1,
    const float* __restrict__ x2, unsigned short* __restrict__ o0,
    unsigned short* __restrict__ o1, unsigned short* __restrict__ o2,
    const float* __restrict__ w0, const float* __restrict__ w1,
    const float* __restrict__ w2, const float* __restrict__ w3,
    unsigned short* __restrict__ t0, unsigned short* __restrict__ t1,
    unsigned short* __restrict__ t2, unsigned short* __restrict__ t3) {
  const int id = blockIdx.x;
  if (id < 1536) {
    const int src = id >> 9, blk = id & 511;
    const float* s = (src == 0) ? x0 : (src == 1) ? x1 : x2;
    unsigned short* d = (src == 0) ? o0 : (src == 1) ? o1 : o2;
    const int n4 = MTOT * DMODEL / 4;
    for (int i = blk * 256 + threadIdx.x; i < n4; i += 512 * 256) {
      float4 f = reinterpret_cast<const float4*>(s)[i];
      ushort4 u;
      u.x = bf16u(f.x); u.y = bf16u(f.y); u.z = bf16u(f.z); u.w = bf16u(f.w);
      reinterpret_cast<ushort4*>(d)[i] = u;
    }
  } else {
    __shared__ float tile[64][65];   // +1 pad: conflict-free column reads
    const int id2 = id - 1536;
    const int wsel = id2 >> 8, tl = id2 & 255;
    const float* w = (wsel == 0) ? w0 : (wsel == 1) ? w1
                     : (wsel == 2) ? w2 : w3;
    unsigned short* t = (wsel == 0) ? t0 : (wsel == 1) ? t1
                        : (wsel == 2) ? t2 : t3;
    const float scl = (wsel == 0) ? QSCALE * LOG2E : 1.0f;
    int n0 = (tl & 15) * 64, k0 = (tl >> 4) * 64;
    int tx = threadIdx.x & 63, ty = threadIdx.x >> 6;
#pragma unroll
    for (int i = 0; i < 16; ++i) {
      int kk = ty * 16 + i;
      tile[kk][tx] = w[(k0 + kk) * DMODEL + n0 + tx];   // coalesced read
    }
    __syncthreads();
#pragma unroll
    for (int i = 0; i < 16; ++i) {
      int nn = ty * 16 + i;
      t[(n0 + nn) * DMODEL + k0 + tx] = bf16u(tile[tx][nn] * scl);
    }
  }
}

// ---- 256x256-tile bf16 GEMM (q/k/v): 512 thr, 1 block/CU, triple-buffer --
// grid (16, 4, 3).  8 waves in 2x4 grid; wave sub-tile 128x64; acc[8][4].
// Same counted-vmcnt protocol: stage = 4 gl16/thread; wait vmcnt(4) at top
// (tile kt landed, kt+1 in flight); single s_barrier; stage(kt+2) after.
// z=0/1: out (B,H,S,64).  z=2: PACKED kappa-fragment V (R17-proven).
// LDS rows 64B (4 x 16B units); unit u of row holds global u^((row>>1)&3).
__global__ __launch_bounds__(512) void gemm_qkv_kernel(
    const unsigned short* __restrict__ xq, const unsigned short* __restrict__ xk,
    const unsigned short* __restrict__ xv,
    const unsigned short* __restrict__ wq, const unsigned short* __restrict__ wk,
    const unsigned short* __restrict__ wv,
    unsigned short* __restrict__ qb, unsigned short* __restrict__ kb,
    unsigned short* __restrict__ vp) {
  __shared__ unsigned short lA[3][256 * 32];
  __shared__ unsigned short lB[3][256 * 32];
  const int z = blockIdx.z;
  const unsigned short* A = (z == 0) ? xq : (z == 1) ? xk : xv;
  const unsigned short* Wt = (z == 0) ? wq : (z == 1) ? wk : wv;
  unsigned short* outb = (z == 0) ? qb : (z == 1) ? kb : vp;

  const int tid = threadIdx.x;
  const int lane = tid & 63, wid = tid >> 6;
  const int wr = wid >> 2, wc = wid & 3;       // 2 x 4 wave grid
  const int m0 = blockIdx.x * 256, n0 = blockIdx.y * 256;
  const int lm = lane & 15, lg = lane >> 4;

  auto stage = [&](int buf, int kt) {
#pragma unroll
    for (int i = 0; i < 2; ++i) {
      int c = tid + i * 512;                   // 0..1023 16B chunks
      int row = c >> 2, cb = c & 3;
      int scb = cb ^ ((row >> 1) & 3);         // pre-swizzled source unit
      gl16(A + (m0 + row) * DMODEL + kt * 32 + scb * 8, (char*)lA[buf] + c * 16);
      gl16(Wt + (n0 + row) * DMODEL + kt * 32 + scb * 8, (char*)lB[buf] + c * 16);
    }
  };

  f32x4 acc[8][4] = {};
  stage(0, 0);           // 4 loads
  stage(1, 1);           // +4 loads (8 outstanding)

  const int NKT = DMODEL / 32;   // 32
  for (int kt = 0; kt < NKT; ++kt) {
    if (kt == NKT - 1) {
      asm volatile("s_waitcnt vmcnt(0)" ::: "memory");
    } else {
      asm volatile("s_waitcnt vmcnt(4)" ::: "memory");
    }
    __builtin_amdgcn_sched_barrier(0);
    __builtin_amdgcn_s_barrier();
    __builtin_amdgcn_sched_barrier(0);

    if (kt + 2 < NKT) stage((kt + 2) % 3, kt + 2);   // overwrite oldest buf

    const int cur = kt % 3;
    bf16x8 af[8], bfr[4];
#pragma unroll
    for (int x = 0; x < 8; ++x) {
      int rowA = wr * 128 + x * 16 + lm;
      int uA = lg ^ ((rowA >> 1) & 3);
      af[x] = *reinterpret_cast<const bf16x8*>(
          (const char*)&lA[cur][0] + rowA * 64 + uA * 16);
    }
#pragma unroll
    for (int y = 0; y < 4; ++y) {
      int rowB = wc * 64 + y * 16 + lm;
      int uB = lg ^ ((rowB >> 1) & 3);
      bfr[y] = *reinterpret_cast<const bf16x8*>(
          (const char*)&lB[cur][0] + rowB * 64 + uB * 16);
    }
#pragma unroll
    for (int mi = 0; mi < 8; ++mi)
#pragma unroll
      for (int ni = 0; ni < 4; ++ni)
        acc[mi][ni] = mfma16(af[mi], bfr[ni], acc[mi][ni]);
  }

  // epilogue.  C/D layout: col = lane&15, row = (lane>>4)*4 + r
  const int lg2 = lane >> 4;
#pragma unroll
  for (int mi = 0; mi < 8; ++mi)
#pragma unroll
    for (int ni = 0; ni < 4; ++ni) {
      int col = n0 + wc * 64 + ni * 16 + lm;
#pragma unroll
      for (int r = 0; r < 4; ++r) {
        int row = m0 + wr * 128 + mi * 16 + lg2 * 4 + r;
        int b = row >> 11, s = row & (SEQ - 1);
        int h = col >> 6, d = col & (HD - 1);
        unsigned short val = bf16u(acc[mi][ni][r]);
        if (z != 2) {
          outb[(((b * NH + h) * SEQ + s) * HD + d)] = val;
        } else {
          int kt2 = s >> 6, rem6 = s & 63;
          int ff = rem6 >> 4, rem = rem6 & 15;
          int jj = (rem & 3) | ((rem >> 3) << 2);
          int hh = (rem >> 2) & 1;
          size_t pidx =
              (((((size_t)(b * NH + h) * 32 + kt2) * 2 + (d >> 5)) * 4 + ff) * 64
               + hh * 32 + (d & 31)) * 8 + jj;
          outb[pidx] = val;
        }
      }
    }
}

// ---- final projection: 128x64 tiles, triple-buffer + vmcnt(3) + swizzle --
__global__ __launch_bounds__(256) void gemm_out_kernel(
    const unsigned short* __restrict__ A, const unsigned short* __restrict__ Wt,
    float* __restrict__ outf) {
  __shared__ unsigned short lA[3][128 * 32];
  __shared__ unsigned short lB[3][64 * 32];
  const int tid = threadIdx.x;
  const int lane = tid & 63, wr = tid >> 6;    // wave owns 32 m-rows
  const int m0 = blockIdx.x * 128, n0 = blockIdx.y * 64;
  const int lm = lane & 15, lg = lane >> 4;

  auto stage = [&](int buf, int kt) {
#pragma unroll
    for (int i = 0; i < 2; ++i) {
      int c = tid + i * 256;
      int row = c >> 2, cb = c & 3;
      int scb = cb ^ ((row >> 1) & 3);
      gl16(A + (m0 + row) * DMODEL + kt * 32 + scb * 8, (char*)lA[buf] + c * 16);
    }
    int c = tid;
    int row = c >> 2, cb = c & 3;
    int scb = cb ^ ((row >> 1) & 3);
    gl16(Wt + (n0 + row) * DMODEL + kt * 32 + scb * 8, (char*)lB[buf] + c * 16);
  };

  f32x4 acc[2][4] = {};
  stage(0, 0);           // 3 loads
  stage(1, 1);           // +3 loads (6 outstanding)

  const int NKT = DMODEL / 32;
  for (int kt = 0; kt < NKT; ++kt) {
    if (kt == NKT - 1) {
      asm volatile("s_waitcnt vmcnt(0)" ::: "memory");
    } else {
      asm volatile("s_waitcnt vmcnt(3)" ::: "memory");
    }
    __builtin_amdgcn_sched_barrier(0);
    __builtin_amdgcn_s_barrier();
    __builtin_amdgcn_sched_barrier(0);

    if (kt + 2 < NKT) stage((kt + 2) % 3, kt + 2);

    const int cur = kt % 3;
    bf16x8 af[2], bfr[4];
#pragma unroll
    for (int x = 0; x < 2; ++x) {
      int rowA = wr * 32 + x * 16 + lm;
      int uA = lg ^ ((rowA >> 1) & 3);
      af[x] = *reinterpret_cast<const bf16x8*>(
          (const char*)&lA[cur][0] + rowA * 64 + uA * 16);
    }
#pragma unroll
    for (int x = 0; x < 4; ++x) {
      int rowB = x * 16 + lm;
      int uB = lg ^ ((rowB >> 1) & 3);
      bfr[x] = *reinterpret_cast<const bf16x8*>(
          (const char*)&lB[cur][0] + rowB * 64 + uB * 16);
    }
#pragma unroll
    for (int mi = 0; mi < 2; ++mi)
#pragma unroll
      for (int ni = 0; ni < 4; ++ni)
        acc[mi][ni] = mfma16(af[mi], bfr[ni], acc[mi][ni]);
  }

  const int lg2 = lane >> 4;
#pragma unroll
  for (int mi = 0; mi < 2; ++mi)
#pragma unroll
    for (int ni = 0; ni < 4; ++ni) {
      int col = n0 + ni * 16 + lm;
#pragma unroll
      for (int r = 0; r < 4; ++r) {
        int row = m0 + wr * 32 + mi * 16 + lg2 * 4 + r;
        outf[row * DMODEL + col] = acc[mi][ni][r];
      }
    }
}

// ---- flash attention: R17/R20 champion body; V via packed coalesced loads --
// qb, kb: (B,H,S,64) bf16;  vp: packed kappa layout (see gemm);  ao: bf16
// One wave owns 32 q-rows; no barriers; K double-buffered per-wave LDS.
// Order (proven optimal vs R15/R16/R22 alternatives): vmcnt(0) pin ->
// readK -> QK^T -> stageK(t+1) -> loadV(t) -> mask/softmax -> packP -> PV.
__global__ __launch_bounds__(256, 2) void attn17_kernel(
    const unsigned short* __restrict__ qb, const unsigned short* __restrict__ kb,
    const unsigned short* __restrict__ vp, const int* __restrict__ vlens,
    unsigned short* __restrict__ ao) {
  __shared__ char klds[4][2][8192];  // [wave][buf][64 keys x 128B], swizzled
  const int lane = threadIdx.x & 63;
  const int w = threadIdx.x >> 6;
  const int qi = lane & 31, hi = lane >> 5;
  const int wid = blockIdx.x * 4 + w;
  const int bhi = wid & 31;          // consecutive waves: alternate batches
  const int chunk = wid >> 5;        // 0..63 (32-row q chunk)
  const int b = bhi & 1, h = bhi >> 1;
  const int bh = b * NH + h;
  const int s0w = chunk * 32;
  const int vlen = vlens[b];
  const int nkt = (vlen + 63) >> 6;

  const unsigned short* kbase = kb + bh * SEQ * HD;
  const unsigned short* vpb = vp + (size_t)bh * 32 * 2 * 4 * 64 * 8;

  // Q fragments (B-operand): col=q=qi, k-slot ks: elems = Q[q][ks*16+hi*8+j]
  const unsigned short* qrow = qb + (bh * SEQ + s0w + qi) * HD;
  bf16x8 qf[4];
#pragma unroll
  for (int ks = 0; ks < 4; ++ks)
    qf[ks] = *reinterpret_cast<const bf16x8*>(qrow + ks * 16 + hi * 8);

  f32x16 oacc[2] = {};     // O^T: col=q, row = d (2 blocks of 32)
  float m = -3e38f, l = 0.f;

  // K staging (linear LDS dest, pre-swizzled global source col) — R9-proven
  const int srow = lane >> 3;
  const int scol8 = (lane & 7) ^ (srow & 7);
  auto stageK = [&](int buf, int kt) {
    int k0 = kt * 64;
    char* dst = &klds[w][buf][0];
#pragma unroll
    for (int i = 0; i < 8; ++i)
      gl16(kbase + (size_t)(k0 + i * 8 + srow) * HD + scol8 * 8,
           dst + i * 1024);
  };

  // frag read: row = kb2*32+qi, byte col = (ks*32+hi*16) ^ ((qi&7)<<4)
  auto readK = [&](bf16x8* kr, int buf) {
    const char* base = &klds[w][buf][0];
#pragma unroll
    for (int kb2 = 0; kb2 < 2; ++kb2)
#pragma unroll
      for (int ks = 0; ks < 4; ++ks) {
        int row = kb2 * 32 + qi;
        int off = row * 128 + ((ks * 32 + hi * 16) ^ ((qi & 7) << 4));
        kr[kb2 * 4 + ks] = *reinterpret_cast<const bf16x8*>(base + off);
      }
  };

  auto body = [&](int t, int buf) {
    const int k0 = t * 64;
    const bool lastt = (t == nkt - 1);

    // K(t) staging (gl16, no register def) must complete before ds_reads;
    // compiler can't track this dependency -> explicit wait + pin (rule #18).
    asm volatile("s_waitcnt vmcnt(0)" ::: "memory");
    __builtin_amdgcn_sched_barrier(0);

    bf16x8 kr[8];
    readK(kr, buf);

    // S^T = K Q^T : lane (q=qi, hi), reg r holds S[key=k0+(32)+g(r,hi)][q]
    f32x16 s0 = {}, s1 = {};
    __builtin_amdgcn_s_setprio(1);
#pragma unroll
    for (int ks = 0; ks < 4; ++ks) s0 = mfma32(kr[ks], qf[ks], s0);
#pragma unroll
    for (int ks = 0; ks < 4; ++ks) s1 = mfma32(kr[4 + ks], qf[ks], s1);
    __builtin_amdgcn_s_setprio(0);

    // prefetch K(t+1), then V(t) packed fragment loads:
    // frag (db,f): lane L reads bf16x8 at tile base + ((db*4+f)*64 + L)*16B
    if (!lastt) stageK(buf ^ 1, t + 1);

    const unsigned short* vtile = vpb + (size_t)t * 2 * 4 * 64 * 8;
    bf16x8 vr[8];
#pragma unroll
    for (int db = 0; db < 2; ++db)
#pragma unroll
      for (int f = 0; f < 4; ++f)
        vr[db * 4 + f] = *reinterpret_cast<const bf16x8*>(
            vtile + ((db * 4 + f) * 64 + lane) * 8);

    if (lastt) {
#pragma unroll
      for (int r = 0; r < 16; ++r) {
        int key = k0 + (r & 3) + 8 * (r >> 2) + 4 * hi;
        if (key >= vlen) s0[r] = -1.4426950e6f;       // MASK_VALUE * log2e
        if (key + 32 >= vlen) s1[r] = -1.4426950e6f;
      }
    }

    // row max: tree + 1 cross-half shuffle
    float mx8[8];
#pragma unroll
    for (int i = 0; i < 8; ++i)
      mx8[i] = fmaxf(fmaxf(s0[i], s0[i + 8]), fmaxf(s1[i], s1[i + 8]));
#pragma unroll
    for (int st = 4; st; st >>= 1)
#pragma unroll
      for (int i = 0; i < st; ++i) mx8[i] = fmaxf(mx8[i], mx8[i + st]);
    float mx = fmaxf(mx8[0], __shfl_xor(mx8[0], 32, 64));
    float mn = fmaxf(m, mx);
    float sf = exp2_fast(m - mn);
    m = mn;

    // exp2 + row sum (tree)
#pragma unroll
    for (int r = 0; r < 16; ++r) s0[r] = exp2_fast(s0[r] - mn);
#pragma unroll
    for (int r = 0; r < 16; ++r) s1[r] = exp2_fast(s1[r] - mn);
    float sm8[8];
#pragma unroll
    for (int i = 0; i < 8; ++i)
      sm8[i] = (s0[i] + s0[i + 8]) + (s1[i] + s1[i + 8]);
#pragma unroll
    for (int st = 4; st; st >>= 1)
#pragma unroll
      for (int i = 0; i < st; ++i) sm8[i] += sm8[i + st];
    float ps = sm8[0] + __shfl_xor(sm8[0], 32, 64);
    l = l * sf + ps;
#pragma unroll
    for (int db = 0; db < 2; ++db) oacc[db] *= sf;

    // P B-frags in RAW register order (layout-invariance, R7/R9-validated)
    bf16x8 pf[4];
    auto packP = [&](const f32x16& s, bf16x8* out) {
#pragma unroll
      for (int f = 0; f < 2; ++f) {
        uint4v wv;
#pragma unroll
        for (int k2 = 0; k2 < 4; ++k2)
          wv[k2] = cvtpk(s[f * 8 + k2 * 2], s[f * 8 + k2 * 2 + 1]);
        out[f] = __builtin_bit_cast(bf16x8, wv);
      }
    };
    packP(s0, pf);
    packP(s1, pf + 2);

    // O^T += V^T P
    __builtin_amdgcn_s_setprio(1);
#pragma unroll
    for (int db = 0; db < 2; ++db)
#pragma unroll
      for (int f = 0; f < 4; ++f)
        oacc[db] = mfma32(vr[db * 4 + f], pf[f], oacc[db]);
    __builtin_amdgcn_s_setprio(0);
  };

  stageK(0, 0);
  for (int t = 0; t < nkt; ++t) body(t, t & 1);

  const float linv = 1.0f / l;
#pragma unroll
  for (int db = 0; db < 2; ++db)
#pragma unroll
    for (int rq = 0; rq < 4; ++rq) {
      ushort4 o;
      o.x = bf16u(oacc[db][rq * 4 + 0] * linv);
      o.y = bf16u(oacc[db][rq * 4 + 1] * linv);
      o.z = bf16u(oacc[db][rq * 4 + 2] * linv);
      o.w = bf16u(oacc[db][rq * 4 + 3] * linv);
      int d = db * 32 + 8 * rq + 4 * hi;
      *reinterpret_cast<ushort4*>(
          ao + (b * SEQ + s0w + qi) * DMODEL + h * HD + d) = o;
    }
}

extern "C" void kernel_launch(void* const* d_in, const int* in_sizes, int n_in,
                              void* d_out, int out_size, void* d_ws, size_t ws_size,
                              hipStream_t stream) {
  (void)in_sizes; (void)n_in; (void)out_size; (void)ws_size;
  const float* q = (const float*)d_in[0];
  const float* k = (const float*)d_in[1];
  const float* v = (const float*)d_in[2];
  const int* vlens = (const int*)d_in[3];
  const float* Wq = (const float*)d_in[4];
  const float* Wk = (const float*)d_in[5];
  const float* Wv = (const float*)d_in[6];
  const float* Wo = (const float*)d_in[7];
  float* out = (float*)d_out;

  char* ws = (char*)d_ws;
  const size_t MB = 1u << 20;
  unsigned short* xq = (unsigned short*)(ws + 0 * MB);   // 8 MB each
  unsigned short* xk = (unsigned short*)(ws + 8 * MB);
  unsigned short* xv = (unsigned short*)(ws + 16 * MB);
  unsigned short* wqt = (unsigned short*)(ws + 24 * MB); // 2 MB each
  unsigned short* wkt = (unsigned short*)(ws + 26 * MB);
  unsigned short* wvt = (unsigned short*)(ws + 28 * MB);
  unsigned short* wot = (unsigned short*)(ws + 30 * MB);
  unsigned short* qb = (unsigned short*)(ws + 32 * MB);  // 8 MB each
  unsigned short* kb = (unsigned short*)(ws + 40 * MB);
  unsigned short* vpk = (unsigned short*)(ws + 48 * MB); // packed V
  unsigned short* ao = (unsigned short*)(ws + 56 * MB);

  prep_kernel<<<dim3(2560), 256, 0, stream>>>(q, k, v, xq, xk, xv,
                                              Wq, Wk, Wv, Wo,
                                              wqt, wkt, wvt, wot);
  gemm_qkv_kernel<<<dim3(16, 4, 3), 512, 0, stream>>>(xq, xk, xv,
                                                      wqt, wkt, wvt,
                                                      qb, kb, vpk);
  attn17_kernel<<<dim3(512), 256, 0, stream>>>(qb, kb, vpk, vlens, ao);
  gemm_out_kernel<<<dim3(32, 16), 256, 0, stream>>>(ao, wot, out);
}

// Round 26
// 105.300 us; speedup vs baseline: 1.1601x; 1.1601x over previous
//
#include <hip/hip_runtime.h>
#include <stdint.h>

#define NH 16
#define SEQ 2048
#define DMODEL 1024
#define HD 64
#define NBATCH 2
#define MTOT (NBATCH * SEQ)              // 4096 rows for the big GEMMs
#define QSCALE 0.17677669529663687f      // 1/sqrt(B*H) = 1/sqrt(32)  (faithful bug)
#define LOG2E 1.4426950408889634f

typedef __bf16 bf16x8 __attribute__((ext_vector_type(8)));
typedef float f32x4 __attribute__((ext_vector_type(4)));
typedef float f32x16 __attribute__((ext_vector_type(16)));
typedef unsigned uint4v __attribute__((ext_vector_type(4)));

// round-to-nearest-even fp32 -> bf16 bit pattern
__device__ __forceinline__ unsigned short bf16u(float x) {
  unsigned u = __builtin_bit_cast(unsigned, x);
  u += 0x7fffu + ((u >> 16) & 1u);
  return (unsigned short)(u >> 16);
}

// 2^x via v_exp_f32 (ISA: D = 2^S0)
__device__ __forceinline__ float exp2_fast(float x) {
  float r;
  asm("v_exp_f32 %0, %1" : "=v"(r) : "v"(x));
  return r;
}

__device__ __forceinline__ f32x4 mfma16(bf16x8 a, bf16x8 b, f32x4 c) {
  return __builtin_amdgcn_mfma_f32_16x16x32_bf16(a, b, c, 0, 0, 0);
}
__device__ __forceinline__ f32x16 mfma32(bf16x8 a, bf16x8 b, f32x16 c) {
  return __builtin_amdgcn_mfma_f32_32x32x16_bf16(a, b, c, 0, 0, 0);
}

__device__ __forceinline__ void gl16(const void* g, void* l) {
  __builtin_amdgcn_global_load_lds(
      (const __attribute__((address_space(1))) void*)g,
      (__attribute__((address_space(3))) void*)l, 16, 0, 0);
}

// pack 2 f32 -> 2 bf16 in one u32 (lo = a, hi = b)
__device__ __forceinline__ unsigned cvtpk(float a, float b) {
  unsigned r;
  asm("v_cvt_pk_bf16_f32 %0, %1, %2" : "=v"(r) : "v"(a), "v"(b));
  return r;
}

// CHAMPION CONFIG (R24, 105.5us — reproduced).  Closed experiment axes:
// permlane32_swap reduces (R4/R10 fail), min-waves clamps (R11 spill),
// K/V reg-dbuf (R15/R21), attn loop reorders (R16/R22), qkv tile 128x64
// (R18) / 256x256 (R25), split-K (R13), block-shared K/V (R14).
// Wins stacked here: packed-kappa V (R17), triple-buffer + counted vmcnt +
// raw s_barrier (R19), both-sides XOR swizzle (R20), XCD swizzle (R24,
// neutral-harmless).

// ---- fused prep: cast x (fp32->bf16) + transpose/cast W ----
__global__ __launch_bounds__(256) void prep_kernel(
    const float* __restrict__ x0, const float* __restrict__ x1,
    const float* __restrict__ x2, unsigned short* __restrict__ o0,
    unsigned short* __restrict__ o1, unsigned short* __restrict__ o2,
    const float* __restrict__ w0, const float* __restrict__ w1,
    const float* __restrict__ w2, const float* __restrict__ w3,
    unsigned short* __restrict__ t0, unsigned short* __restrict__ t1,
    unsigned short* __restrict__ t2, unsigned short* __restrict__ t3) {
  const int id = blockIdx.x;
  if (id < 1536) {
    const int src = id >> 9, blk = id & 511;
    const float* s = (src == 0) ? x0 : (src == 1) ? x1 : x2;
    unsigned short* d = (src == 0) ? o0 : (src == 1) ? o1 : o2;
    const int n4 = MTOT * DMODEL / 4;
    for (int i = blk * 256 + threadIdx.x; i < n4; i += 512 * 256) {
      float4 f = reinterpret_cast<const float4*>(s)[i];
      ushort4 u;
      u.x = bf16u(f.x); u.y = bf16u(f.y); u.z = bf16u(f.z); u.w = bf16u(f.w);
      reinterpret_cast<ushort4*>(d)[i] = u;
    }
  } else {
    __shared__ float tile[64][65];   // +1 pad: conflict-free column reads
    const int id2 = id - 1536;
    const int wsel = id2 >> 8, tl = id2 & 255;
    const float* w = (wsel == 0) ? w0 : (wsel == 1) ? w1
                     : (wsel == 2) ? w2 : w3;
    unsigned short* t = (wsel == 0) ? t0 : (wsel == 1) ? t1
                        : (wsel == 2) ? t2 : t3;
    const float scl = (wsel == 0) ? QSCALE * LOG2E : 1.0f;
    int n0 = (tl & 15) * 64, k0 = (tl >> 4) * 64;
    int tx = threadIdx.x & 63, ty = threadIdx.x >> 6;
#pragma unroll
    for (int i = 0; i < 16; ++i) {
      int kk = ty * 16 + i;
      tile[kk][tx] = w[(k0 + kk) * DMODEL + n0 + tx];   // coalesced read
    }
    __syncthreads();
#pragma unroll
    for (int i = 0; i < 16; ++i) {
      int nn = ty * 16 + i;
      t[(n0 + nn) * DMODEL + k0 + tx] = bf16u(tile[tx][nn] * scl);
    }
  }
}

// ---- 128x128-tile bf16 GEMM (q/k/v): triple-buffer + vmcnt(4) + swizzle --
// grid (768) 1-D, XCD-swizzled decode: r=bid&7 (XCD under round-robin),
// j=bid>>3; bx=(r>>1)*8+(j&7); by=(r&1)*4+((j>>3)&3); z=j>>5.  Bijective
// onto (32,8,3).  z=0/1: out (B,H,S,64).  z=2: PACKED kappa-fragment V
// (R17-proven algebra).  LDS rows are 64B (4 x 16B units); unit u of row
// holds global unit u ^ ((row>>1)&3); reads XOR the same way.
__global__ __launch_bounds__(256) void gemm_qkv_kernel(
    const unsigned short* __restrict__ xq, const unsigned short* __restrict__ xk,
    const unsigned short* __restrict__ xv,
    const unsigned short* __restrict__ wq, const unsigned short* __restrict__ wk,
    const unsigned short* __restrict__ wv,
    unsigned short* __restrict__ qb, unsigned short* __restrict__ kb,
    unsigned short* __restrict__ vp) {
  __shared__ unsigned short lA[3][128 * 32];
  __shared__ unsigned short lB[3][128 * 32];
  const int bid = blockIdx.x;
  const int rr = bid & 7, jj0 = bid >> 3;
  const int bx = (rr >> 1) * 8 + (jj0 & 7);
  const int by = (rr & 1) * 4 + ((jj0 >> 3) & 3);
  const int z = jj0 >> 5;
  const unsigned short* A = (z == 0) ? xq : (z == 1) ? xk : xv;
  const unsigned short* Wt = (z == 0) ? wq : (z == 1) ? wk : wv;
  unsigned short* outb = (z == 0) ? qb : (z == 1) ? kb : vp;

  const int tid = threadIdx.x;
  const int lane = tid & 63, wid = tid >> 6;
  const int wr = wid >> 1, wc = wid & 1;
  const int m0 = bx * 128, n0 = by * 128;
  const int lm = lane & 15, lg = lane >> 4;

  auto stage = [&](int buf, int kt) {
#pragma unroll
    for (int i = 0; i < 2; ++i) {
      int c = tid + i * 256;
      int row = c >> 2, cb = c & 3;
      int scb = cb ^ ((row >> 1) & 3);   // pre-swizzled source 16B unit
      gl16(A + (m0 + row) * DMODEL + kt * 32 + scb * 8, (char*)lA[buf] + c * 16);
      gl16(Wt + (n0 + row) * DMODEL + kt * 32 + scb * 8, (char*)lB[buf] + c * 16);
    }
  };

  f32x4 acc[4][4] = {};
  stage(0, 0);           // 4 loads
  stage(1, 1);           // +4 loads (8 outstanding)

  const int NKT = DMODEL / 32;   // 32
  for (int kt = 0; kt < NKT; ++kt) {
    if (kt == NKT - 1) {
      asm volatile("s_waitcnt vmcnt(0)" ::: "memory");
    } else {
      asm volatile("s_waitcnt vmcnt(4)" ::: "memory");
    }
    __builtin_amdgcn_sched_barrier(0);
    __builtin_amdgcn_s_barrier();
    __builtin_amdgcn_sched_barrier(0);

    if (kt + 2 < NKT) stage((kt + 2) % 3, kt + 2);   // overwrite oldest buf

    const int cur = kt % 3;
    bf16x8 af[4], bfr[4];
#pragma unroll
    for (int x = 0; x < 4; ++x) {
      int rowA = wr * 64 + x * 16 + lm;
      int rowB = wc * 64 + x * 16 + lm;
      int uA = lg ^ ((rowA >> 1) & 3);
      int uB = lg ^ ((rowB >> 1) & 3);
      af[x] = *reinterpret_cast<const bf16x8*>(
          (const char*)&lA[cur][0] + rowA * 64 + uA * 16);
      bfr[x] = *reinterpret_cast<const bf16x8*>(
          (const char*)&lB[cur][0] + rowB * 64 + uB * 16);
    }
#pragma unroll
    for (int mi = 0; mi < 4; ++mi)
#pragma unroll
      for (int ni = 0; ni < 4; ++ni)
        acc[mi][ni] = mfma16(af[mi], bfr[ni], acc[mi][ni]);
  }

  // epilogue.  C/D layout: col = lane&15, row = (lane>>4)*4 + r
  const int lg2 = lane >> 4;
#pragma unroll
  for (int mi = 0; mi < 4; ++mi)
#pragma unroll
    for (int ni = 0; ni < 4; ++ni) {
      int col = n0 + wc * 64 + ni * 16 + lm;
#pragma unroll
      for (int r = 0; r < 4; ++r) {
        int row = m0 + wr * 64 + mi * 16 + lg2 * 4 + r;
        int b = row >> 11, s = row & (SEQ - 1);
        int h = col >> 6, d = col & (HD - 1);
        unsigned short val = bf16u(acc[mi][ni][r]);
        if (z != 2) {
          outb[(((b * NH + h) * SEQ + s) * HD + d)] = val;
        } else {
          int kt2 = s >> 6, rem6 = s & 63;
          int ff = rem6 >> 4, rem = rem6 & 15;
          int jj = (rem & 3) | ((rem >> 3) << 2);
          int hh = (rem >> 2) & 1;
          size_t pidx =
              (((((size_t)(b * NH + h) * 32 + kt2) * 2 + (d >> 5)) * 4 + ff) * 64
               + hh * 32 + (d & 31)) * 8 + jj;
          outb[pidx] = val;
        }
      }
    }
}

// ---- final projection: 128x64 tiles, triple-buffer + vmcnt(3) + swizzle --
__global__ __launch_bounds__(256) void gemm_out_kernel(
    const unsigned short* __restrict__ A, const unsigned short* __restrict__ Wt,
    float* __restrict__ outf) {
  __shared__ unsigned short lA[3][128 * 32];
  __shared__ unsigned short lB[3][64 * 32];
  const int tid = threadIdx.x;
  const int lane = tid & 63, wr = tid >> 6;    // wave owns 32 m-rows
  const int m0 = blockIdx.x * 128, n0 = blockIdx.y * 64;
  const int lm = lane & 15, lg = lane >> 4;

  auto stage = [&](int buf, int kt) {
#pragma unroll
    for (int i = 0; i < 2; ++i) {
      int c = tid + i * 256;
      int row = c >> 2, cb = c & 3;
      int scb = cb ^ ((row >> 1) & 3);
      gl16(A + (m0 + row) * DMODEL + kt * 32 + scb * 8, (char*)lA[buf] + c * 16);
    }
    int c = tid;
    int row = c >> 2, cb = c & 3;
    int scb = cb ^ ((row >> 1) & 3);
    gl16(Wt + (n0 + row) * DMODEL + kt * 32 + scb * 8, (char*)lB[buf] + c * 16);
  };

  f32x4 acc[2][4] = {};
  stage(0, 0);           // 3 loads
  stage(1, 1);           // +3 loads (6 outstanding)

  const int NKT = DMODEL / 32;
  for (int kt = 0; kt < NKT; ++kt) {
    if (kt == NKT - 1) {
      asm volatile("s_waitcnt vmcnt(0)" ::: "memory");
    } else {
      asm volatile("s_waitcnt vmcnt(3)" ::: "memory");
    }
    __builtin_amdgcn_sched_barrier(0);
    __builtin_amdgcn_s_barrier();
    __builtin_amdgcn_sched_barrier(0);

    if (kt + 2 < NKT) stage((kt + 2) % 3, kt + 2);

    const int cur = kt % 3;
    bf16x8 af[2], bfr[4];
#pragma unroll
    for (int x = 0; x < 2; ++x) {
      int rowA = wr * 32 + x * 16 + lm;
      int uA = lg ^ ((rowA >> 1) & 3);
      af[x] = *reinterpret_cast<const bf16x8*>(
          (const char*)&lA[cur][0] + rowA * 64 + uA * 16);
    }
#pragma unroll
    for (int x = 0; x < 4; ++x) {
      int rowB = x * 16 + lm;
      int uB = lg ^ ((rowB >> 1) & 3);
      bfr[x] = *reinterpret_cast<const bf16x8*>(
          (const char*)&lB[cur][0] + rowB * 64 + uB * 16);
    }
#pragma unroll
    for (int mi = 0; mi < 2; ++mi)
#pragma unroll
      for (int ni = 0; ni < 4; ++ni)
        acc[mi][ni] = mfma16(af[mi], bfr[ni], acc[mi][ni]);
  }

  const int lg2 = lane >> 4;
#pragma unroll
  for (int mi = 0; mi < 2; ++mi)
#pragma unroll
    for (int ni = 0; ni < 4; ++ni) {
      int col = n0 + ni * 16 + lm;
#pragma unroll
      for (int r = 0; r < 4; ++r) {
        int row = m0 + wr * 32 + mi * 16 + lg2 * 4 + r;
        outf[row * DMODEL + col] = acc[mi][ni][r];
      }
    }
}

// ---- flash attention: R17/R20 champion body; V via packed coalesced loads --
// qb, kb: (B,H,S,64) bf16;  vp: packed kappa layout (see gemm);  ao: bf16
// One wave owns 32 q-rows; no barriers; K double-buffered per-wave LDS.
// Order (proven optimal vs R15/R16/R22 alternatives): vmcnt(0) pin ->
// readK -> QK^T -> stageK(t+1) -> loadV(t) -> mask/softmax -> packP -> PV.
__global__ __launch_bounds__(256, 2) void attn17_kernel(
    const unsigned short* __restrict__ qb, const unsigned short* __restrict__ kb,
    const unsigned short* __restrict__ vp, const int* __restrict__ vlens,
    unsigned short* __restrict__ ao) {
  __shared__ char klds[4][2][8192];  // [wave][buf][64 keys x 128B], swizzled
  const int lane = threadIdx.x & 63;
  const int w = threadIdx.x >> 6;
  const int qi = lane & 31, hi = lane >> 5;
  const int wid = blockIdx.x * 4 + w;
  const int bhi = wid & 31;          // consecutive waves: alternate batches
  const int chunk = wid >> 5;        // 0..63 (32-row q chunk)
  const int b = bhi & 1, h = bhi >> 1;
  const int bh = b * NH + h;
  const int s0w = chunk * 32;
  const int vlen = vlens[b];
  const int nkt = (vlen + 63) >> 6;

  const unsigned short* kbase = kb + bh * SEQ * HD;
  const unsigned short* vpb = vp + (size_t)bh * 32 * 2 * 4 * 64 * 8;

  // Q fragments (B-operand): col=q=qi, k-slot ks: elems = Q[q][ks*16+hi*8+j]
  const unsigned short* qrow = qb + (bh * SEQ + s0w + qi) * HD;
  bf16x8 qf[4];
#pragma unroll
  for (int ks = 0; ks < 4; ++ks)
    qf[ks] = *reinterpret_cast<const bf16x8*>(qrow + ks * 16 + hi * 8);

  f32x16 oacc[2] = {};     // O^T: col=q, row = d (2 blocks of 32)
  float m = -3e38f, l = 0.f;

  // K staging (linear LDS dest, pre-swizzled global source col) — R9-proven
  const int srow = lane >> 3;
  const int scol8 = (lane & 7) ^ (srow & 7);
  auto stageK = [&](int buf, int kt) {
    int k0 = kt * 64;
    char* dst = &klds[w][buf][0];
#pragma unroll
    for (int i = 0; i < 8; ++i)
      gl16(kbase + (size_t)(k0 + i * 8 + srow) * HD + scol8 * 8,
           dst + i * 1024);
  };

  // frag read: row = kb2*32+qi, byte col = (ks*32+hi*16) ^ ((qi&7)<<4)
  auto readK = [&](bf16x8* kr, int buf) {
    const char* base = &klds[w][buf][0];
#pragma unroll
    for (int kb2 = 0; kb2 < 2; ++kb2)
#pragma unroll
      for (int ks = 0; ks < 4; ++ks) {
        int row = kb2 * 32 + qi;
        int off = row * 128 + ((ks * 32 + hi * 16) ^ ((qi & 7) << 4));
        kr[kb2 * 4 + ks] = *reinterpret_cast<const bf16x8*>(base + off);
      }
  };

  auto body = [&](int t, int buf) {
    const int k0 = t * 64;
    const bool lastt = (t == nkt - 1);

    // K(t) staging (gl16, no register def) must complete before ds_reads;
    // compiler can't track this dependency -> explicit wait + pin (rule #18).
    asm volatile("s_waitcnt vmcnt(0)" ::: "memory");
    __builtin_amdgcn_sched_barrier(0);

    bf16x8 kr[8];
    readK(kr, buf);

    // S^T = K Q^T : lane (q=qi, hi), reg r holds S[key=k0+(32)+g(r,hi)][q]
    f32x16 s0 = {}, s1 = {};
    __builtin_amdgcn_s_setprio(1);
#pragma unroll
    for (int ks = 0; ks < 4; ++ks) s0 = mfma32(kr[ks], qf[ks], s0);
#pragma unroll
    for (int ks = 0; ks < 4; ++ks) s1 = mfma32(kr[4 + ks], qf[ks], s1);
    __builtin_amdgcn_s_setprio(0);

    // prefetch K(t+1), then V(t) packed fragment loads:
    // frag (db,f): lane L reads bf16x8 at tile base + ((db*4+f)*64 + L)*16B
    if (!lastt) stageK(buf ^ 1, t + 1);

    const unsigned short* vtile = vpb + (size_t)t * 2 * 4 * 64 * 8;
    bf16x8 vr[8];
#pragma unroll
    for (int db = 0; db < 2; ++db)
#pragma unroll
      for (int f = 0; f < 4; ++f)
        vr[db * 4 + f] = *reinterpret_cast<const bf16x8*>(
            vtile + ((db * 4 + f) * 64 + lane) * 8);

    if (lastt) {
#pragma unroll
      for (int r = 0; r < 16; ++r) {
        int key = k0 + (r & 3) + 8 * (r >> 2) + 4 * hi;
        if (key >= vlen) s0[r] = -1.4426950e6f;       // MASK_VALUE * log2e
        if (key + 32 >= vlen) s1[r] = -1.4426950e6f;
      }
    }

    // row max: tree + 1 cross-half shuffle
    float mx8[8];
#pragma unroll
    for (int i = 0; i < 8; ++i)
      mx8[i] = fmaxf(fmaxf(s0[i], s0[i + 8]), fmaxf(s1[i], s1[i + 8]));
#pragma unroll
    for (int st = 4; st; st >>= 1)
#pragma unroll
      for (int i = 0; i < st; ++i) mx8[i] = fmaxf(mx8[i], mx8[i + st]);
    float mx = fmaxf(mx8[0], __shfl_xor(mx8[0], 32, 64));
    float mn = fmaxf(m, mx);
    float sf = exp2_fast(m - mn);
    m = mn;

    // exp2 + row sum (tree)
#pragma unroll
    for (int r = 0; r < 16; ++r) s0[r] = exp2_fast(s0[r] - mn);
#pragma unroll
    for (int r = 0; r < 16; ++r) s1[r] = exp2_fast(s1[r] - mn);
    float sm8[8];
#pragma unroll
    for (int i = 0; i < 8; ++i)
      sm8[i] = (s0[i] + s0[i + 8]) + (s1[i] + s1[i + 8]);
#pragma unroll
    for (int st = 4; st; st >>= 1)
#pragma unroll
      for (int i = 0; i < st; ++i) sm8[i] += sm8[i + st];
    float ps = sm8[0] + __shfl_xor(sm8[0], 32, 64);
    l = l * sf + ps;
#pragma unroll
    for (int db = 0; db < 2; ++db) oacc[db] *= sf;

    // P B-frags in RAW register order (layout-invariance, R7/R9-validated)
    bf16x8 pf[4];
    auto packP = [&](const f32x16& s, bf16x8* out) {
#pragma unroll
      for (int f = 0; f < 2; ++f) {
        uint4v wv;
#pragma unroll
        for (int k2 = 0; k2 < 4; ++k2)
          wv[k2] = cvtpk(s[f * 8 + k2 * 2], s[f * 8 + k2 * 2 + 1]);
        out[f] = __builtin_bit_cast(bf16x8, wv);
      }
    };
    packP(s0, pf);
    packP(s1, pf + 2);

    // O^T += V^T P
    __builtin_amdgcn_s_setprio(1);
#pragma unroll
    for (int db = 0; db < 2; ++db)
#pragma unroll
      for (int f = 0; f < 4; ++f)
        oacc[db] = mfma32(vr[db * 4 + f], pf[f], oacc[db]);
    __builtin_amdgcn_s_setprio(0);
  };

  stageK(0, 0);
  for (int t = 0; t < nkt; ++t) body(t, t & 1);

  const float linv = 1.0f / l;
#pragma unroll
  for (int db = 0; db < 2; ++db)
#pragma unroll
    for (int rq = 0; rq < 4; ++rq) {
      ushort4 o;
      o.x = bf16u(oacc[db][rq * 4 + 0] * linv);
      o.y = bf16u(oacc[db][rq * 4 + 1] * linv);
      o.z = bf16u(oacc[db][rq * 4 + 2] * linv);
      o.w = bf16u(oacc[db][rq * 4 + 3] * linv);
      int d = db * 32 + 8 * rq + 4 * hi;
      *reinterpret_cast<ushort4*>(
          ao + (b * SEQ + s0w + qi) * DMODEL + h * HD + d) = o;
    }
}

extern "C" void kernel_launch(void* const* d_in, const int* in_sizes, int n_in,
                              void* d_out, int out_size, void* d_ws, size_t ws_size,
                              hipStream_t stream) {
  (void)in_sizes; (void)n_in; (void)out_size; (void)ws_size;
  const float* q = (const float*)d_in[0];
  const float* k = (const float*)d_in[1];
  const float* v = (const float*)d_in[2];
  const int* vlens = (const int*)d_in[3];
  const float* Wq = (const float*)d_in[4];
  const float* Wk = (const float*)d_in[5];
  const float* Wv = (const float*)d_in[6];
  const float* Wo = (const float*)d_in[7];
  float* out = (float*)d_out;

  char* ws = (char*)d_ws;
  const size_t MB = 1u << 20;
  unsigned short* xq = (unsigned short*)(ws + 0 * MB);   // 8 MB each
  unsigned short* xk = (unsigned short*)(ws + 8 * MB);
  unsigned short* xv = (unsigned short*)(ws + 16 * MB);
  unsigned short* wqt = (unsigned short*)(ws + 24 * MB); // 2 MB each
  unsigned short* wkt = (unsigned short*)(ws + 26 * MB);
  unsigned short* wvt = (unsigned short*)(ws + 28 * MB);
  unsigned short* wot = (unsigned short*)(ws + 30 * MB);
  unsigned short* qb = (unsigned short*)(ws + 32 * MB);  // 8 MB each
  unsigned short* kb = (unsigned short*)(ws + 40 * MB);
  unsigned short* vpk = (unsigned short*)(ws + 48 * MB); // packed V
  unsigned short* ao = (unsigned short*)(ws + 56 * MB);

  prep_kernel<<<dim3(2560), 256, 0, stream>>>(q, k, v, xq, xk, xv,
                                              Wq, Wk, Wv, Wo,
                                              wqt, wkt, wvt, wot);
  gemm_qkv_kernel<<<dim3(768), 256, 0, stream>>>(xq, xk, xv,
                                                 wqt, wkt, wvt,
                                                 qb, kb, vpk);
  attn17_kernel<<<dim3(512), 256, 0, stream>>>(qb, kb, vpk, vlens, ao);
  gemm_out_kernel<<<dim3(32, 16), 256, 0, stream>>>(ao, wot, out);
}